// Round 1
// baseline (461.103 us; speedup 1.0000x reference)
//
#include <hip/hip_runtime.h>
#include <hip/hip_bf16.h>

// BayesianKAN_ECG: x[65536,1000] f32 -> pool10 -> norm(ddof=1) -> KAN1(RBF16,
// 100->64) -> tanh -> norm -> KAN2(RBF16, 64->5) -> fp32 out [65536,5].
//
// R6: full restructure to barrier-free single-wave blocks.
//  - 4096 blocks x 64 threads; each wave owns 16 rows end-to-end.
//  - A-fragments (RBF basis) computed in registers: for mfma_16x16x32_bf16,
//    lane (q,l15) needs basis(x[l15][i], centers[n0..n0+7]) with i=2ks+(q>>1),
//    n0=(q&1)*8 -> 1 LDS read + 8 exps per fragment. No b1c staging.
//  - B-fragments (weights) loaded directly from global (c1b 205KB L2-resident,
//    layout [col][k] matches fragment need). No c1c staging.
//  - All phases touch only the wave's own 16 rows -> no cross-wave deps,
//    barriers are wave-trivial. hb aliases xn (same-wave LDS ordering).
//  - LDS 6464 B/block -> 16 blocks/CU resident (grid 4096 = 16/CU exactly).

#define SEQ    1000
#define INDIM  100
#define HID    64
#define OUTD   5
#define NB     16
#define ROWS   16
#define NTHR   64

typedef __bf16 v8bf __attribute__((ext_vector_type(8)));
typedef float  v4f  __attribute__((ext_vector_type(4)));

#define XSTR 101   // xn stride (f32): 5r mod 32 distinct -> 2-way max (free)
#define HSTR 65    // hb stride (f32): (r + i) mod 32 -> 2-way max (free)

// ---- pre-kernel: c1 -> bf16 [64][1600], c2 -> bf16 [16][1024] (rows>=5 zero)
__global__ __launch_bounds__(256) void cvt_w(
    const float* __restrict__ c1, const float* __restrict__ c2,
    __bf16* __restrict__ c1b, __bf16* __restrict__ c2b)
{
  int t = blockIdx.x * 256 + threadIdx.x;
  if (t < 25600) {                       // c1: 102,400 elems = 25,600 quads
    float4 v = ((const float4*)c1)[t];
    __bf16* d = c1b + t * 4;
    d[0] = (__bf16)v.x; d[1] = (__bf16)v.y; d[2] = (__bf16)v.z; d[3] = (__bf16)v.w;
  }
  if (t < 4096) {                        // c2 padded: 16x1024 = 4,096 quads
    int o = t >> 8;
    __bf16* d = c2b + t * 4;
    if (o < OUTD) {
      float4 v = ((const float4*)c2)[t];
      d[0] = (__bf16)v.x; d[1] = (__bf16)v.y; d[2] = (__bf16)v.z; d[3] = (__bf16)v.w;
    } else {
      d[0] = (__bf16)0.f; d[1] = (__bf16)0.f; d[2] = (__bf16)0.f; d[3] = (__bf16)0.f;
    }
  }
}

__global__ __launch_bounds__(NTHR, 4) void kan_main(
    const float* __restrict__ x, const __bf16* __restrict__ c1b,
    const __bf16* __restrict__ c2bw, const float* __restrict__ cen,
    float* __restrict__ out)
{
  __shared__ __align__(16) float sm[ROWS * XSTR];  // 6464 B
  float* xn = sm;                                  // [16][101]
  float* hb = sm;                                  // [16][65], aliases xn

  const int tid  = threadIdx.x;                    // one wave: tid == lane
  const int row0 = blockIdx.x * ROWS;
  const int l15 = tid & 15, q = tid >> 4, iq = q >> 1;

  // exp(-0.5 d^2/0.36) = exp(-(Sn*d)^2), Sn = sqrt(0.5/0.36)
  const float Sn = 1.17851130f;
  float cs[8];
  {
    const int n0 = (q & 1) * 8;                    // fragment layout: n = n0+j
    #pragma unroll
    for (int j = 0; j < 8; ++j) cs[j] = cen[n0 + j] * Sn;
  }

  // ---- pool: mean over 10; thread handles a pooled PAIR (20 contig floats,
  //      float4-aligned since rows start at multiples of 1000) ----
  #pragma unroll
  for (int it = 0; it < 13; ++it) {
    int idx = tid + it * NTHR;                     // < 800 = 16 rows x 50 pairs
    if (idx < 800) {
      int r = idx / 50, p = idx - r * 50;
      const float4* xp = (const float4*)(x + (size_t)(row0 + r) * SEQ + p * 20);
      float4 a0 = xp[0], a1 = xp[1], a2 = xp[2], a3 = xp[3], a4 = xp[4];
      float s0 = a0.x + a0.y + a0.z + a0.w + a1.x + a1.y + a1.z + a1.w + a2.x + a2.y;
      float s1 = a2.z + a2.w + a3.x + a3.y + a3.z + a3.w + a4.x + a4.y + a4.z + a4.w;
      xn[r * XSTR + 2 * p]     = s0 * 0.1f;
      xn[r * XSTR + 2 * p + 1] = s1 * 0.1f;
    }
  }
  __syncthreads();                                 // single wave: trivial

  // ---- norm x: 16 rows, 100 elems, wave shuffle reduce ----
  #pragma unroll
  for (int rr = 0; rr < 16; ++rr) {
    float v0 = xn[rr * XSTR + tid];
    float v1 = (tid < 36) ? xn[rr * XSTR + 64 + tid] : 0.f;
    float s = v0 + v1, s2 = v0 * v0 + v1 * v1;
    #pragma unroll
    for (int m = 32; m; m >>= 1) { s += __shfl_xor(s, m, 64); s2 += __shfl_xor(s2, m, 64); }
    float mu = s * (1.f / INDIM);
    float var = (s2 - INDIM * mu * mu) * (1.f / (INDIM - 1));
    float rs = 1.f / (sqrtf(fmaxf(var, 0.f)) + 1e-6f);
    xn[rr * XSTR + tid] = (v0 - mu) * rs;
    if (tid < 36) xn[rr * XSTR + 64 + tid] = (v1 - mu) * rs;
  }
  __syncthreads();

  // ---- KAN1: 16 rows x 64 out, K=1600; basis in registers, weights from L2 ----
  const float* xrow = xn + l15 * XSTR;
  const __bf16* bp0 = c1b + (size_t)(l15)      * 1600 + q * 8;
  const __bf16* bp1 = c1b + (size_t)(16 + l15) * 1600 + q * 8;
  const __bf16* bp2 = c1b + (size_t)(32 + l15) * 1600 + q * 8;
  const __bf16* bp3 = c1b + (size_t)(48 + l15) * 1600 + q * 8;
  v4f acc0 = {0.f, 0.f, 0.f, 0.f}, acc1 = acc0, acc2 = acc0, acc3 = acc0;

  #pragma unroll 2
  for (int c = 0; c < 10; ++c) {
    #pragma unroll
    for (int ks = 0; ks < 5; ++ks) {
      int ko = c * 160 + ks * 32;
      float xv = xrow[c * 10 + 2 * ks + iq] * Sn;
      v8bf a;
      #pragma unroll
      for (int j = 0; j < 8; ++j) {
        float d = xv - cs[j];
        a[j] = (__bf16)__expf(-(d * d));
      }
      v8bf b0 = *(const v8bf*)(bp0 + ko);
      v8bf b1 = *(const v8bf*)(bp1 + ko);
      v8bf b2 = *(const v8bf*)(bp2 + ko);
      v8bf b3 = *(const v8bf*)(bp3 + ko);
      acc0 = __builtin_amdgcn_mfma_f32_16x16x32_bf16(a, b0, acc0, 0, 0, 0);
      acc1 = __builtin_amdgcn_mfma_f32_16x16x32_bf16(a, b1, acc1, 0, 0, 0);
      acc2 = __builtin_amdgcn_mfma_f32_16x16x32_bf16(a, b2, acc2, 0, 0, 0);
      acc3 = __builtin_amdgcn_mfma_f32_16x16x32_bf16(a, b3, acc3, 0, 0, 0);
    }
  }
  __syncthreads();

  // ---- tanh -> hb (D layout: row = q*4+rg, col = cb*16+l15) ----
  auto tanh_store = [&](v4f a, int cb) {
    #pragma unroll
    for (int rg = 0; rg < 4; ++rg) {
      float t = a[rg];
      float e = __expf(t + t);
      hb[(q * 4 + rg) * HSTR + cb * 16 + l15] = 1.f - 2.f / (e + 1.f);
    }
  };
  tanh_store(acc0, 0); tanh_store(acc1, 1); tanh_store(acc2, 2); tanh_store(acc3, 3);
  __syncthreads();

  // ---- norm h: 16 rows, 64 elems ----
  #pragma unroll
  for (int rr = 0; rr < 16; ++rr) {
    float v = hb[rr * HSTR + tid];
    float s = v, s2 = v * v;
    #pragma unroll
    for (int m = 32; m; m >>= 1) { s += __shfl_xor(s, m, 64); s2 += __shfl_xor(s2, m, 64); }
    float mu = s * (1.f / HID);
    float var = (s2 - HID * mu * mu) * (1.f / (HID - 1));
    float rs = 1.f / (sqrtf(fmaxf(var, 0.f)) + 1e-6f);
    hb[rr * HSTR + tid] = (v - mu) * rs;
  }
  __syncthreads();

  // ---- KAN2: 16 rows x 16(5) out, K=1024, full K per wave, no reduction ----
  const float* hrow = hb + l15 * HSTR;
  const __bf16* bp4 = c2bw + (size_t)l15 * 1024 + q * 8;
  v4f o4 = {0.f, 0.f, 0.f, 0.f};
  #pragma unroll 8
  for (int t8 = 0; t8 < 32; ++t8) {
    float hv = hrow[2 * t8 + iq] * Sn;
    v8bf a;
    #pragma unroll
    for (int j = 0; j < 8; ++j) {
      float d = hv - cs[j];
      a[j] = (__bf16)__expf(-(d * d));
    }
    v8bf vb = *(const v8bf*)(bp4 + t8 * 32);
    o4 = __builtin_amdgcn_mfma_f32_16x16x32_bf16(a, vb, o4, 0, 0, 0);
  }

  // ---- store: row = q*4+rg, col = l15 (<5) ----
  if (l15 < OUTD) {
    #pragma unroll
    for (int rg = 0; rg < 4; ++rg)
      out[(size_t)(row0 + q * 4 + rg) * OUTD + l15] = o4[rg];
  }
}

extern "C" void kernel_launch(void* const* d_in, const int* in_sizes, int n_in,
                              void* d_out, int out_size, void* d_ws, size_t ws_size,
                              hipStream_t stream) {
  const float* x   = (const float*)d_in[0];
  const float* c1  = (const float*)d_in[1];
  const float* c2  = (const float*)d_in[2];
  const float* cen = (const float*)d_in[3];
  float* out = (float*)d_out;

  __bf16* c1b = (__bf16*)d_ws;                         // 204,800 B
  __bf16* c2b = (__bf16*)((char*)d_ws + 204800);       //  32,768 B

  hipLaunchKernelGGL(cvt_w, dim3(100), dim3(256), 0, stream, c1, c2, c1b, c2b);
  hipLaunchKernelGGL(kan_main, dim3(65536 / ROWS), dim3(NTHR), 0, stream,
                     x, c1b, c2b, cen, out);
}

// Round 2
// 451.817 us; speedup vs baseline: 1.0206x; 1.0206x over previous
//
#include <hip/hip_runtime.h>
#include <hip/hip_bf16.h>

// BayesianKAN_ECG: x[65536,1000] f32 -> pool10 -> norm(ddof=1) -> KAN1(RBF16,
// 100->64) -> tanh -> norm -> KAN2(RBF16, 64->5) -> fp32 out [65536,5].
//
// R7: occupancy + instruction-count attack (R6 was latency-bound at 4
// waves/SIMD, 20% issue rate; compute-only replays showed 170us even with
// zero HBM traffic).
//  - 2-wave blocks (128 thr), 16 rows/block, K-SPLIT: wave w does K-half of
//    KAN1 (c = 5w..5w+4) and KAN2 (t8 = 16w..16w+15); partials combined in
//    LDS. 8192 waves -> 32 waves/CU (was 16).
//  - norm-x fused into pool: per-thread partials + 3 shuffles (was 384 ds ops).
//  - norm-h in registers on the MFMA acc (per-lane partial over col-blocks +
//    4-level shuffle), split by rg-pair across the two waves (was 192 ds ops).
//  - exp2 with log2e folded into center/input scale; x,h stored PRE-SCALED by
//    Sn' = sqrt(0.5/0.36*log2e) so the basis is exp2(-(xv-cs)^2) = 3 VALU/elem.
//  - raw v_rcp/v_sqrt for norms + tanh (error ~1e-7, tolerance 0.012).
//  - pooling x0.1 dropped (norm scale-invariant); eps 1e-6 -> 1e-5 exactly.

#define SEQ    1000
#define INDIM  100
#define HID    64
#define OUTD   5
#define ROWS   16
#define NTHR   128

typedef __bf16 v8bf __attribute__((ext_vector_type(8)));
typedef float  v4f  __attribute__((ext_vector_type(4)));

#define XSTR 101   // xn stride (f32)
#define HSTR 65    // hb stride (f32)
#define RSTR 68    // red stride (f32)
#define R2STR 20   // red2 stride (f32)

#if __has_builtin(__builtin_amdgcn_exp2f)
#define EXP2(x) __builtin_amdgcn_exp2f(x)
#else
#define EXP2(x) exp2f(x)
#endif
#if __has_builtin(__builtin_amdgcn_rcpf)
#define RCP(x) __builtin_amdgcn_rcpf(x)
#else
#define RCP(x) (1.f / (x))
#endif
#if __has_builtin(__builtin_amdgcn_sqrtf)
#define SQRT(x) __builtin_amdgcn_sqrtf(x)
#else
#define SQRT(x) sqrtf(x)
#endif

// ---- pre-kernel: c1 -> bf16 [64][1600], c2 -> bf16 [16][1024] (rows>=5 zero)
__global__ __launch_bounds__(256) void cvt_w(
    const float* __restrict__ c1, const float* __restrict__ c2,
    __bf16* __restrict__ c1b, __bf16* __restrict__ c2b)
{
  int t = blockIdx.x * 256 + threadIdx.x;
  if (t < 25600) {
    float4 v = ((const float4*)c1)[t];
    __bf16* d = c1b + t * 4;
    d[0] = (__bf16)v.x; d[1] = (__bf16)v.y; d[2] = (__bf16)v.z; d[3] = (__bf16)v.w;
  }
  if (t < 4096) {
    int o = t >> 8;
    __bf16* d = c2b + t * 4;
    if (o < OUTD) {
      float4 v = ((const float4*)c2)[t];
      d[0] = (__bf16)v.x; d[1] = (__bf16)v.y; d[2] = (__bf16)v.z; d[3] = (__bf16)v.w;
    } else {
      d[0] = (__bf16)0.f; d[1] = (__bf16)0.f; d[2] = (__bf16)0.f; d[3] = (__bf16)0.f;
    }
  }
}

__global__ __launch_bounds__(NTHR, 8) void kan_main(
    const float* __restrict__ x, const __bf16* __restrict__ c1b,
    const __bf16* __restrict__ c2bw, const float* __restrict__ cen,
    float* __restrict__ out)
{
  // LDS (floats), phases alias:
  //  P1: xn[16][101] @0            (1616)
  //  P2: red[16][68] @0 (1088, overwrites dead xn), hb[16][65] @1088 (1040)
  //  P3: red2[16][20] @0 (320, red consumed)
  __shared__ __align__(16) float sm[2128];   // 8512 B -> 16 blocks/CU
  float* xn   = sm;
  float* red  = sm;
  float* hb   = sm + 1088;
  float* red2 = sm;

  const int tid  = threadIdx.x;
  const int w    = tid >> 6, lane = tid & 63;
  const int row0 = blockIdx.x * ROWS;
  const int l15 = lane & 15, q = lane >> 4, iq = q >> 1;

  // exp(-0.5 d^2/0.36) = exp2(-((d*Sn2)^2)), Sn2 = sqrt(0.5/0.36 * log2 e)
  const float Sn2 = 1.41553628f;
  const float TL2 = 2.88539008f;             // 2*log2(e) for tanh
  float cs[8];
  {
    const int n0 = (q & 1) * 8;
    #pragma unroll
    for (int j = 0; j < 8; ++j) cs[j] = cen[n0 + j] * Sn2;
  }

  // ---- pool + norm-x fused: thread = (row pr, slot), partial sums in regs,
  //      3-level shuffle reduce over the 8-slot group. Raw sums (no /10):
  //      norm is scale-invariant; eps 1e-6 -> 1e-5 compensates exactly. ----
  const int pr   = (w << 3) + (lane & 7);    // row 0..15
  const int slot = lane >> 3;                // 0..7 (within wave)
  float pva[14];
  float s = 0.f, s2 = 0.f;
  {
    const float* xg = x + (size_t)(row0 + pr) * SEQ;
    #pragma unroll
    for (int it = 0; it < 7; ++it) {
      int p = slot + (it << 3);
      float u0 = 0.f, u1 = 0.f;
      if (p < 50) {
        const float4* xp = (const float4*)(xg + p * 20);
        float4 a0 = xp[0], a1 = xp[1], a2 = xp[2], a3 = xp[3], a4 = xp[4];
        u0 = a0.x+a0.y+a0.z+a0.w + a1.x+a1.y+a1.z+a1.w + a2.x+a2.y;
        u1 = a2.z+a2.w + a3.x+a3.y+a3.z+a3.w + a4.x+a4.y+a4.z+a4.w;
        s += u0 + u1; s2 += u0*u0 + u1*u1;
      }
      pva[2*it] = u0; pva[2*it+1] = u1;
    }
  }
  #pragma unroll
  for (int m = 8; m <= 32; m <<= 1) {
    s += __shfl_xor(s, m, 64); s2 += __shfl_xor(s2, m, 64);
  }
  {
    float mu  = s * 0.01f;
    float var = (s2 - 100.f * mu * mu) * (1.f / 99.f);
    float rs  = Sn2 * RCP(SQRT(fmaxf(var, 0.f)) + 1e-5f);
    #pragma unroll
    for (int it = 0; it < 7; ++it) {
      int p = slot + (it << 3);
      if (p < 50) {
        xn[pr * XSTR + 2*p]     = (pva[2*it]     - mu) * rs;  // pre-scaled by Sn2
        xn[pr * XSTR + 2*p + 1] = (pva[2*it + 1] - mu) * rs;
      }
    }
  }
  __syncthreads();

  // ---- KAN1 (K-split): wave w does chunks c = 5w..5w+4 (K=800) ----
  const float* xr = xn + l15 * XSTR;
  const __bf16* bq = c1b + q * 8;
  v4f acc[4];
  acc[0] = (v4f){0.f,0.f,0.f,0.f}; acc[1] = acc[0]; acc[2] = acc[0]; acc[3] = acc[0];

  #pragma unroll 2
  for (int c5 = 0; c5 < 5; ++c5) {
    int c = w * 5 + c5;
    #pragma unroll
    for (int ks = 0; ks < 5; ++ks) {
      float xv = xr[c * 10 + 2 * ks + iq];           // already * Sn2
      v8bf a;
      #pragma unroll
      for (int j = 0; j < 8; ++j) {
        float d = xv - cs[j];
        a[j] = (__bf16)EXP2(-(d * d));
      }
      int ko = c * 160 + ks * 32;
      #pragma unroll
      for (int cb = 0; cb < 4; ++cb) {
        v8bf b = *(const v8bf*)(bq + (size_t)(cb * 16 + l15) * 1600 + ko);
        acc[cb] = __builtin_amdgcn_mfma_f32_16x16x32_bf16(a, b, acc[cb], 0, 0, 0);
      }
    }
  }
  __syncthreads();

  // ---- combine partials: wave w gives away rg = {2(1-w), 2(1-w)+1},
  //      owns rg = {2w, 2w+1}; tanh + in-register norm-h on own rows ----
  #pragma unroll
  for (int rgo = 0; rgo < 2; ++rgo) {
    int rg = 2 * (1 - w) + rgo;
    #pragma unroll
    for (int cb = 0; cb < 4; ++cb)
      red[(q * 4 + rg) * RSTR + cb * 16 + l15] = acc[cb][rg];
  }
  __syncthreads();
  #pragma unroll
  for (int rgo = 0; rgo < 2; ++rgo) {
    int rg = 2 * w + rgo;
    float h[4], ss = 0.f, ss2 = 0.f;
    #pragma unroll
    for (int cb = 0; cb < 4; ++cb) {
      float t = acc[cb][rg] + red[(q * 4 + rg) * RSTR + cb * 16 + l15];
      float e = EXP2(t * TL2);                       // e^{2t}
      float hv = 1.f - 2.f * RCP(e + 1.f);           // tanh
      h[cb] = hv; ss += hv; ss2 += hv * hv;
    }
    #pragma unroll
    for (int m = 1; m <= 8; m <<= 1) {
      ss += __shfl_xor(ss, m, 64); ss2 += __shfl_xor(ss2, m, 64);
    }
    float muh  = ss * (1.f / 64.f);
    float varh = (ss2 - 64.f * muh * muh) * (1.f / 63.f);
    float rsh  = Sn2 * RCP(SQRT(fmaxf(varh, 0.f)) + 1e-6f);
    #pragma unroll
    for (int cb = 0; cb < 4; ++cb)
      hb[(q * 4 + rg) * HSTR + cb * 16 + l15] = (h[cb] - muh) * rsh;  // pre-scaled
  }
  __syncthreads();

  // ---- KAN2 (K-split): wave w does t8 = 16w..16w+15 (K=512) ----
  const float* hr = hb + l15 * HSTR;
  const __bf16* bq2 = c2bw + (size_t)l15 * 1024 + q * 8;
  v4f o4 = (v4f){0.f, 0.f, 0.f, 0.f};
  #pragma unroll 4
  for (int t = 0; t < 16; ++t) {
    int t8 = w * 16 + t;
    float hv = hr[2 * t8 + iq];                      // already * Sn2
    v8bf a;
    #pragma unroll
    for (int j = 0; j < 8; ++j) {
      float d = hv - cs[j];
      a[j] = (__bf16)EXP2(-(d * d));
    }
    v8bf vb = *(const v8bf*)(bq2 + t8 * 32);
    o4 = __builtin_amdgcn_mfma_f32_16x16x32_bf16(a, vb, o4, 0, 0, 0);
  }
  if (w == 0) {
    #pragma unroll
    for (int rg = 0; rg < 4; ++rg)
      red2[(q * 4 + rg) * R2STR + l15] = o4[rg];
  }
  __syncthreads();
  if (w == 1 && l15 < OUTD) {
    #pragma unroll
    for (int rg = 0; rg < 4; ++rg) {
      int r = q * 4 + rg;
      out[(size_t)(row0 + r) * OUTD + l15] = o4[rg] + red2[r * R2STR + l15];
    }
  }
}

extern "C" void kernel_launch(void* const* d_in, const int* in_sizes, int n_in,
                              void* d_out, int out_size, void* d_ws, size_t ws_size,
                              hipStream_t stream) {
  const float* x   = (const float*)d_in[0];
  const float* c1  = (const float*)d_in[1];
  const float* c2  = (const float*)d_in[2];
  const float* cen = (const float*)d_in[3];
  float* out = (float*)d_out;

  __bf16* c1b = (__bf16*)d_ws;                         // 204,800 B
  __bf16* c2b = (__bf16*)((char*)d_ws + 204800);       //  32,768 B

  hipLaunchKernelGGL(cvt_w, dim3(100), dim3(256), 0, stream, c1, c2, c1b, c2b);
  hipLaunchKernelGGL(kan_main, dim3(65536 / ROWS), dim3(NTHR), 0, stream,
                     x, c1b, c2b, cen, out);
}

// Round 3
// 400.994 us; speedup vs baseline: 1.1499x; 1.1267x over previous
//
#include <hip/hip_runtime.h>
#include <hip/hip_bf16.h>

// BayesianKAN_ECG: x[65536,1000] f32 -> pool10 -> norm(ddof=1) -> KAN1(RBF16,
// 100->64) -> tanh -> norm -> KAN2(RBF16, 64->5) -> fp32 out [65536,5].
//
// R8: memory-request-path attack. R7 showed 84% occupancy with VALUBusy 14%
// -> waves co-stalled on shared L1/L2 request throughput, not TLP.
//  - Weights pre-permuted to FRAGMENT-MAJOR layout: each MFMA B-fragment is a
//    contiguous 1KB block, loaded as base + lane*16B (8 full lines/instr,
//    was 16 half-used lines with 3200B lane strides). Waves sweep the same
//    contiguous 100KB in order -> L1 temporal hits across waves.
//  - Pool lane-map transposed (pr = lane>>3, slot = lane&7): 8 lanes cover
//    640B contiguous per row (R7 had adjacent lanes 4000B apart).
//  - Explicit 1-ahead B prefetch; xv/hv LDS scalars batched; launch_bounds
//    (128,6) gives ~80 VGPRs for the pipeline (R7's 32 VGPRs serialized it).
//  - Keep R7 skeleton: 2-wave blocks, 16 rows, K-split KAN1/KAN2, fused
//    pool+norm-x, in-register norm-h, exp2 with pre-scaled inputs.

#define SEQ    1000
#define INDIM  100
#define HID    64
#define OUTD   5
#define ROWS   16
#define NTHR   128

typedef __bf16 v8bf __attribute__((ext_vector_type(8)));
typedef float  v4f  __attribute__((ext_vector_type(4)));

#define XSTR 101   // xn stride (f32)
#define HSTR 65    // hb stride (f32)
#define RSTR 68    // red stride (f32)
#define R2STR 20   // red2 stride (f32)

#if __has_builtin(__builtin_amdgcn_exp2f)
#define EXP2(x) __builtin_amdgcn_exp2f(x)
#else
#define EXP2(x) exp2f(x)
#endif
#if __has_builtin(__builtin_amdgcn_rcpf)
#define RCP(x) __builtin_amdgcn_rcpf(x)
#else
#define RCP(x) (1.f / (x))
#endif
#if __has_builtin(__builtin_amdgcn_sqrtf)
#define SQRT(x) __builtin_amdgcn_sqrtf(x)
#else
#define SQRT(x) sqrtf(x)
#endif

// ---- pre-kernel: permute weights to fragment-major bf16.
// c1p: frag f = ks*4+cb (ks 0..49, cb 0..3); elem off = f*512 + lane*8,
//      lane=(q<<4)|l15 holds c1[row=cb*16+l15][col=ks*32+q*8 .. +7].
// c2p: frag t8 0..31; lane holds c2[row=l15][col=t8*32+q*8 .. +7], row>=5 zero.
__global__ __launch_bounds__(256) void cvt_w(
    const float* __restrict__ c1, const float* __restrict__ c2,
    __bf16* __restrict__ c1p, __bf16* __restrict__ c2p)
{
  int t = blockIdx.x * 256 + threadIdx.x;
  if (t < 12800) {
    int lane = t & 63, frag = t >> 6;
    int cb = frag & 3, ks = frag >> 2;
    int l15 = lane & 15, q = lane >> 4;
    const float4* s = (const float4*)(c1 + (size_t)(cb * 16 + l15) * 1600 + ks * 32 + q * 8);
    float4 v0 = s[0], v1 = s[1];
    __bf16* d = c1p + (size_t)t * 8;
    d[0]=(__bf16)v0.x; d[1]=(__bf16)v0.y; d[2]=(__bf16)v0.z; d[3]=(__bf16)v0.w;
    d[4]=(__bf16)v1.x; d[5]=(__bf16)v1.y; d[6]=(__bf16)v1.z; d[7]=(__bf16)v1.w;
  }
  if (t < 2048) {
    int lane = t & 63, t8 = t >> 6;
    int row = lane & 15, q = lane >> 4;
    __bf16* d = c2p + (size_t)t * 8;
    if (row < OUTD) {
      const float4* s = (const float4*)(c2 + (size_t)row * 1024 + t8 * 32 + q * 8);
      float4 v0 = s[0], v1 = s[1];
      d[0]=(__bf16)v0.x; d[1]=(__bf16)v0.y; d[2]=(__bf16)v0.z; d[3]=(__bf16)v0.w;
      d[4]=(__bf16)v1.x; d[5]=(__bf16)v1.y; d[6]=(__bf16)v1.z; d[7]=(__bf16)v1.w;
    } else {
      #pragma unroll
      for (int j = 0; j < 8; ++j) d[j] = (__bf16)0.f;
    }
  }
}

#define MFMA __builtin_amdgcn_mfma_f32_16x16x32_bf16

__global__ __launch_bounds__(NTHR, 6) void kan_main(
    const float* __restrict__ x, const __bf16* __restrict__ c1p,
    const __bf16* __restrict__ c2p, const float* __restrict__ cen,
    float* __restrict__ out)
{
  // LDS (floats), phases alias:
  //  P1: xn[16][101] @0 (1616)
  //  P2: red[16][68] @0 (1088), hb[16][65] @1088 (1040)
  //  P3: red2[16][20] @0 (320)
  __shared__ __align__(16) float sm[2128];   // 8512 B
  float* xn   = sm;
  float* red  = sm;
  float* hb   = sm + 1088;
  float* red2 = sm;

  const int tid  = threadIdx.x;
  const int w    = tid >> 6, lane = tid & 63;
  const int row0 = blockIdx.x * ROWS;
  const int l15 = lane & 15, q = lane >> 4, iq = q >> 1;

  // exp(-0.5 d^2/0.36) = exp2(-((d*Sn2)^2)), Sn2 = sqrt(0.5/0.36 * log2 e)
  const float Sn2 = 1.41553628f;
  const float TL2 = 2.88539008f;             // 2*log2(e) for tanh
  float cs[8];
  {
    const int n0 = (q & 1) * 8;
    #pragma unroll
    for (int j = 0; j < 8; ++j) cs[j] = cen[n0 + j] * Sn2;
  }

  // ---- pool + norm-x fused. Lane map: pr = lane>>3 (row), slot = lane&7.
  //      8 lanes of one row read 640B contiguous -> line-dense. Raw sums
  //      (no /10): norm scale-invariant, eps 1e-6 -> 1e-5 exactly. ----
  const int pr   = (w << 3) + (lane >> 3);
  const int slot = lane & 7;
  float pva[14];
  float s = 0.f, s2 = 0.f;
  {
    const float* xg = x + (size_t)(row0 + pr) * SEQ;
    #pragma unroll
    for (int it = 0; it < 7; ++it) {
      int p = slot + (it << 3);
      float u0 = 0.f, u1 = 0.f;
      if (p < 50) {
        const float4* xp = (const float4*)(xg + p * 20);
        float4 a0 = xp[0], a1 = xp[1], a2 = xp[2], a3 = xp[3], a4 = xp[4];
        u0 = a0.x+a0.y+a0.z+a0.w + a1.x+a1.y+a1.z+a1.w + a2.x+a2.y;
        u1 = a2.z+a2.w + a3.x+a3.y+a3.z+a3.w + a4.x+a4.y+a4.z+a4.w;
        s += u0 + u1; s2 += u0*u0 + u1*u1;
      }
      pva[2*it] = u0; pva[2*it+1] = u1;
    }
  }
  #pragma unroll
  for (int m = 1; m <= 4; m <<= 1) {
    s += __shfl_xor(s, m, 64); s2 += __shfl_xor(s2, m, 64);
  }
  {
    float mu  = s * 0.01f;
    float var = (s2 - 100.f * mu * mu) * (1.f / 99.f);
    float rs  = Sn2 * RCP(SQRT(fmaxf(var, 0.f)) + 1e-5f);
    #pragma unroll
    for (int it = 0; it < 7; ++it) {
      int p = slot + (it << 3);
      if (p < 50) {
        xn[pr * XSTR + 2*p]     = (pva[2*it]     - mu) * rs;  // pre-scaled by Sn2
        xn[pr * XSTR + 2*p + 1] = (pva[2*it + 1] - mu) * rs;
      }
    }
  }
  __syncthreads();

  // ---- KAN1 (K-split): wave w does global ksteps 25w..25w+24 (K=800).
  //      B-fragments contiguous: frag (ks*4+cb)*512 elems; 1-ahead prefetch.
  const float* xr = xn + l15 * XSTR;
  const __bf16* bp = c1p + (size_t)(51200 * w) + lane * 8;
  v4f acc[4];
  acc[0] = (v4f){0.f,0.f,0.f,0.f}; acc[1] = acc[0]; acc[2] = acc[0]; acc[3] = acc[0];

  v8bf bA0 = *(const v8bf*)(bp +    0);
  v8bf bA1 = *(const v8bf*)(bp +  512);
  v8bf bA2 = *(const v8bf*)(bp + 1024);
  v8bf bA3 = *(const v8bf*)(bp + 1536);
  bp += 2048;

  #pragma unroll
  for (int c5 = 0; c5 < 5; ++c5) {
    const int c = w * 5 + c5;
    float xv[5];
    #pragma unroll
    for (int k = 0; k < 5; ++k) xv[k] = xr[c * 10 + 2 * k + iq];
    #pragma unroll
    for (int ks = 0; ks < 5; ++ks) {
      v8bf nb0, nb1, nb2, nb3;
      if (c5 * 5 + ks < 24) {
        nb0 = *(const v8bf*)(bp +    0);
        nb1 = *(const v8bf*)(bp +  512);
        nb2 = *(const v8bf*)(bp + 1024);
        nb3 = *(const v8bf*)(bp + 1536);
      }
      bp += 2048;
      v8bf a;
      {
        float xvk = xv[ks];
        #pragma unroll
        for (int j = 0; j < 8; ++j) {
          float d = xvk - cs[j];
          a[j] = (__bf16)EXP2(-(d * d));
        }
      }
      acc[0] = MFMA(a, bA0, acc[0], 0, 0, 0);
      acc[1] = MFMA(a, bA1, acc[1], 0, 0, 0);
      acc[2] = MFMA(a, bA2, acc[2], 0, 0, 0);
      acc[3] = MFMA(a, bA3, acc[3], 0, 0, 0);
      if (c5 * 5 + ks < 24) { bA0 = nb0; bA1 = nb1; bA2 = nb2; bA3 = nb3; }
    }
  }
  __syncthreads();

  // ---- combine K-halves: wave w gives away rg = {2(1-w),...}, owns {2w,..};
  //      tanh + in-register norm-h on own rows ----
  #pragma unroll
  for (int rgo = 0; rgo < 2; ++rgo) {
    int rg = 2 * (1 - w) + rgo;
    #pragma unroll
    for (int cb = 0; cb < 4; ++cb)
      red[(q * 4 + rg) * RSTR + cb * 16 + l15] = acc[cb][rg];
  }
  __syncthreads();
  #pragma unroll
  for (int rgo = 0; rgo < 2; ++rgo) {
    int rg = 2 * w + rgo;
    float h[4], ss = 0.f, ss2 = 0.f;
    #pragma unroll
    for (int cb = 0; cb < 4; ++cb) {
      float t = acc[cb][rg] + red[(q * 4 + rg) * RSTR + cb * 16 + l15];
      float e = EXP2(t * TL2);                       // e^{2t}
      float hv = 1.f - 2.f * RCP(e + 1.f);           // tanh
      h[cb] = hv; ss += hv; ss2 += hv * hv;
    }
    #pragma unroll
    for (int m = 1; m <= 8; m <<= 1) {
      ss += __shfl_xor(ss, m, 64); ss2 += __shfl_xor(ss2, m, 64);
    }
    float muh  = ss * (1.f / 64.f);
    float varh = (ss2 - 64.f * muh * muh) * (1.f / 63.f);
    float rsh  = Sn2 * RCP(SQRT(fmaxf(varh, 0.f)) + 1e-6f);
    #pragma unroll
    for (int cb = 0; cb < 4; ++cb)
      hb[(q * 4 + rg) * HSTR + cb * 16 + l15] = (h[cb] - muh) * rsh;  // pre-scaled
  }
  __syncthreads();

  // ---- KAN2 (K-split): wave w does t8 = 16w..16w+15 (K=512); contiguous
  //      fragments, 1-ahead prefetch, hv batch-loaded ----
  const float* hr = hb + l15 * HSTR;
  float hv16[16];
  #pragma unroll
  for (int t = 0; t < 16; ++t) hv16[t] = hr[2 * (16 * w + t) + iq];
  const __bf16* bp2 = c2p + (size_t)(16 * w) * 512 + lane * 8;
  v8bf vb = *(const v8bf*)(bp2);
  v4f o4 = (v4f){0.f, 0.f, 0.f, 0.f};
  #pragma unroll
  for (int t = 0; t < 16; ++t) {
    v8bf nvb;
    if (t < 15) nvb = *(const v8bf*)(bp2 + (t + 1) * 512);
    v8bf a;
    {
      float hvv = hv16[t];
      #pragma unroll
      for (int j = 0; j < 8; ++j) {
        float d = hvv - cs[j];
        a[j] = (__bf16)EXP2(-(d * d));
      }
    }
    o4 = MFMA(a, vb, o4, 0, 0, 0);
    if (t < 15) vb = nvb;
  }
  if (w == 0) {
    #pragma unroll
    for (int rg = 0; rg < 4; ++rg)
      red2[(q * 4 + rg) * R2STR + l15] = o4[rg];
  }
  __syncthreads();
  if (w == 1 && l15 < OUTD) {
    #pragma unroll
    for (int rg = 0; rg < 4; ++rg) {
      int r = q * 4 + rg;
      out[(size_t)(row0 + r) * OUTD + l15] = o4[rg] + red2[r * R2STR + l15];
    }
  }
}

extern "C" void kernel_launch(void* const* d_in, const int* in_sizes, int n_in,
                              void* d_out, int out_size, void* d_ws, size_t ws_size,
                              hipStream_t stream) {
  const float* x   = (const float*)d_in[0];
  const float* c1  = (const float*)d_in[1];
  const float* c2  = (const float*)d_in[2];
  const float* cen = (const float*)d_in[3];
  float* out = (float*)d_out;

  __bf16* c1p = (__bf16*)d_ws;                         // 204,800 B
  __bf16* c2p = (__bf16*)((char*)d_ws + 204800);       //  32,768 B

  hipLaunchKernelGGL(cvt_w, dim3(50), dim3(256), 0, stream, c1, c2, c1p, c2p);
  hipLaunchKernelGGL(kan_main, dim3(65536 / ROWS), dim3(NTHR), 0, stream,
                     x, c1p, c2p, cen, out);
}